// Round 1
// baseline (438.684 us; speedup 1.0000x reference)
//
#include <hip/hip_runtime.h>
#include <hip/hip_bf16.h>
#include <stdint.h>

// ---------------------------------------------------------------------------
// Compile-time octahedral tables (replicates the reference's itertools order)
// ---------------------------------------------------------------------------
struct Tab {
    int shift[24][24];   // shift[z][g] = index of R_z^{-1} R_g
    int rot[24][27];     // rot[g][j]   = source flat index for rotated 3x3x3 tap j
};

constexpr Tab make_tab() {
    Tab t{};
    int mats[24][3][3] = {};
    {
        const int perms[6][3] = {{0,1,2},{0,2,1},{1,0,2},{1,2,0},{2,0,1},{2,1,0}};
        const int sgns[8][3]  = {{1,1,1},{1,1,-1},{1,-1,1},{1,-1,-1},
                                 {-1,1,1},{-1,1,-1},{-1,-1,1},{-1,-1,-1}};
        int n = 0;
        for (int pi = 0; pi < 6; ++pi)
            for (int si = 0; si < 8; ++si) {
                int M[3][3] = {};
                for (int i = 0; i < 3; ++i) M[i][perms[pi][i]] = sgns[si][i];
                int det = M[0][0]*(M[1][1]*M[2][2]-M[1][2]*M[2][1])
                        - M[0][1]*(M[1][0]*M[2][2]-M[1][2]*M[2][0])
                        + M[0][2]*(M[1][0]*M[2][1]-M[1][1]*M[2][0]);
                if (det == 1) {
                    for (int i = 0; i < 3; ++i)
                        for (int j = 0; j < 3; ++j) mats[n][i][j] = M[i][j];
                    ++n;
                }
            }
    }
    // shift[g][h]: index k with mats[k] == mats[g]^T @ mats[h]
    for (int g = 0; g < 24; ++g)
        for (int h = 0; h < 24; ++h) {
            int P[3][3] = {};
            for (int i = 0; i < 3; ++i)
                for (int j = 0; j < 3; ++j) {
                    int s = 0;
                    for (int e = 0; e < 3; ++e) s += mats[g][e][i] * mats[h][e][j];
                    P[i][j] = s;
                }
            for (int k = 0; k < 24; ++k) {
                bool eq = true;
                for (int i = 0; i < 3; ++i)
                    for (int j = 0; j < 3; ++j)
                        if (mats[k][i][j] != P[i][j]) eq = false;
                if (eq) t.shift[g][h] = k;
            }
        }
    // rot[g][j]: src = (coord - 1) @ mats[g] + 1
    for (int g = 0; g < 24; ++g)
        for (int j = 0; j < 27; ++j) {
            int co[3] = { j/9 - 1, (j/3)%3 - 1, j%3 - 1 };
            int src[3] = {};
            for (int d = 0; d < 3; ++d) {
                int s = 0;
                for (int e = 0; e < 3; ++e) s += co[e] * mats[g][e][d];
                src[d] = s + 1;
            }
            t.rot[g][j] = src[0]*9 + src[1]*3 + src[2];
        }
    return t;
}

__constant__ Tab TAB = make_tab();

// problem constants
#define GG 24
#define OO 16
#define II 16
#define PVOL 32768          // 32*32*32
#define MCH 384             // O*G
#define KCH 384             // I*G

// ---------------------------------------------------------------------------
// Kernel 1: build Wmix[384][384] and rotated taps Wt[384][27]
//   Wmix[c=o*24+z][k=i*24+g] = g_weight[shift[z][g]][o][i]
//   Wt[c=o*24+z][j]          = t_weight[o][rot[z][j]]
// ---------------------------------------------------------------------------
__global__ void build_weights(const float* __restrict__ gw, const float* __restrict__ tw,
                              float* __restrict__ wmix, float* __restrict__ wt) {
    int idx = blockIdx.x * 256 + threadIdx.x;
    if (idx < MCH * KCH) {
        int c = idx / KCH, k = idx % KCH;
        int o = c / GG, z = c % GG;
        int i = k / GG, g = k % GG;
        wmix[idx] = gw[TAB.shift[z][g] * (OO * II) + o * II + i];
    } else {
        int r = idx - MCH * KCH;
        if (r < MCH * 27) {
            int c = r / 27, j = r % 27;
            wt[r] = tw[(c / GG) * 27 + TAB.rot[c % GG][j]];
        }
    }
}

// ---------------------------------------------------------------------------
// Kernel 2: SGEMM  Y[b][c][p] = sum_k Wmix[c][k] * X[b][k][p] + g_bias[c/24]
//   M=384, K=384, N=32768 per batch. 128x128 tile, BK=16, 256 thr, 8x8/thread
// ---------------------------------------------------------------------------
#define BM 128
#define BN 128
#define BK 16

__global__ __launch_bounds__(256) void gemm_mix(const float* __restrict__ A,
                                                const float* __restrict__ X,
                                                const float* __restrict__ gbias,
                                                float* __restrict__ Y) {
    const int b  = blockIdx.z;
    const int m0 = blockIdx.y * BM;
    const int n0 = blockIdx.x * BN;
    const float* __restrict__ Bp = X + (size_t)b * KCH * PVOL;
    float* __restrict__ Yp = Y + (size_t)b * MCH * PVOL;

    __shared__ float As[BK][BM];
    __shared__ float Bs[BK][BN];

    const int tid = threadIdx.x;
    const int tx = tid % 16;
    const int ty = tid / 16;

    float acc[8][8] = {};

    for (int k0 = 0; k0 < KCH; k0 += BK) {
        // A tile: 128 x 16 = 512 float4, 2 per thread (store transposed)
        #pragma unroll
        for (int r = 0; r < 2; ++r) {
            int t = tid + r * 256;
            int m = t / 4;
            int kk = (t % 4) * 4;
            float4 v = *(const float4*)&A[(m0 + m) * KCH + k0 + kk];
            As[kk + 0][m] = v.x; As[kk + 1][m] = v.y;
            As[kk + 2][m] = v.z; As[kk + 3][m] = v.w;
        }
        // B tile: 16 x 128 = 512 float4, 2 per thread
        #pragma unroll
        for (int r = 0; r < 2; ++r) {
            int t = tid + r * 256;
            int kk = t / 32;
            int n = (t % 32) * 4;
            *(float4*)&Bs[kk][n] = *(const float4*)&Bp[(size_t)(k0 + kk) * PVOL + n0 + n];
        }
        __syncthreads();
        #pragma unroll
        for (int kk = 0; kk < BK; ++kk) {
            float af[8], bf[8];
            #pragma unroll
            for (int i = 0; i < 4; ++i) {
                af[i]     = As[kk][ty * 4 + i];
                af[4 + i] = As[kk][64 + ty * 4 + i];
                bf[i]     = Bs[kk][tx * 4 + i];
                bf[4 + i] = Bs[kk][64 + tx * 4 + i];
            }
            #pragma unroll
            for (int i = 0; i < 8; ++i)
                #pragma unroll
                for (int j = 0; j < 8; ++j)
                    acc[i][j] += af[i] * bf[j];
        }
        __syncthreads();
    }

    #pragma unroll
    for (int i = 0; i < 8; ++i) {
        int m = m0 + ((i < 4) ? (ty * 4 + i) : (64 + ty * 4 + (i - 4)));
        float bias = gbias[m / GG];
        float4 v0 = { acc[i][0] + bias, acc[i][1] + bias, acc[i][2] + bias, acc[i][3] + bias };
        float4 v1 = { acc[i][4] + bias, acc[i][5] + bias, acc[i][6] + bias, acc[i][7] + bias };
        *(float4*)&Yp[(size_t)m * PVOL + n0 + tx * 4]      = v0;
        *(float4*)&Yp[(size_t)m * PVOL + n0 + 64 + tx * 4] = v1;
    }
}

// ---------------------------------------------------------------------------
// Kernel 3: depthwise 3x3x3 conv (pad 1) + t_bias + leaky_relu(0.01)
//   One block per (b, c, x-slab of 8). LDS slab [10][34][34] zero-padded.
//   Sliding-window along x: 9 new LDS reads per output.
// ---------------------------------------------------------------------------
__global__ __launch_bounds__(256) void dwconv(const float* __restrict__ Y,
                                              const float* __restrict__ Wt,
                                              const float* __restrict__ tb,
                                              float* __restrict__ O) {
    const int x0 = blockIdx.x * 8;
    const int c  = blockIdx.y;
    const int b  = blockIdx.z;
    const float* __restrict__ Yc = Y + ((size_t)(b * MCH + c)) * PVOL;
    float* __restrict__ Oc = O + ((size_t)(b * MCH + c)) * PVOL;

    __shared__ float s[10][34][34];
    __shared__ float taps[27];
    const int tid = threadIdx.x;

    // zero LDS (covers padding borders)
    for (int i = tid; i < 10 * 34 * 34; i += 256) ((float*)s)[i] = 0.f;
    if (tid < 27) taps[tid] = Wt[c * 27 + tid];
    __syncthreads();

    // load interior planes
    {
        int yy = tid / 8;
        int zz = (tid % 8) * 4;
        for (int lx = 0; lx < 10; ++lx) {
            int x = x0 - 1 + lx;
            if (x < 0 || x >= 32) continue;
            float4 v = *(const float4*)&Yc[x * 1024 + yy * 32 + zz];
            s[lx][1 + yy][1 + zz + 0] = v.x;
            s[lx][1 + yy][1 + zz + 1] = v.y;
            s[lx][1 + yy][1 + zz + 2] = v.z;
            s[lx][1 + yy][1 + zz + 3] = v.w;
        }
    }
    __syncthreads();

    const float t0 = tb[0];
    float w[27];
    #pragma unroll
    for (int j = 0; j < 27; ++j) w[j] = taps[j];

    const int z = tid % 32;
    const int ybase = tid / 32;   // 0..7

    for (int yi = 0; yi < 4; ++yi) {
        const int y = ybase + yi * 8;
        float p0[9], p1[9], p2[9];
        #pragma unroll
        for (int dy = 0; dy < 3; ++dy)
            #pragma unroll
            for (int dz = 0; dz < 3; ++dz) {
                p0[dy * 3 + dz] = s[0][y + dy][z + dz];
                p1[dy * 3 + dz] = s[1][y + dy][z + dz];
            }
        #pragma unroll
        for (int xi = 0; xi < 8; ++xi) {
            #pragma unroll
            for (int q = 0; q < 9; ++q) p2[q] = s[xi + 2][y + (q / 3)][z + (q % 3)];
            float acc = 0.f;
            #pragma unroll
            for (int q = 0; q < 9; ++q) {
                acc += p0[q] * w[q];
                acc += p1[q] * w[9 + q];
                acc += p2[q] * w[18 + q];
            }
            #pragma unroll
            for (int q = 0; q < 9; ++q) { p0[q] = p1[q]; p1[q] = p2[q]; }
            float v = acc + t0;
            Oc[(x0 + xi) * 1024 + y * 32 + z] = (v > 0.f) ? v : 0.01f * v;
        }
    }
}

// ---------------------------------------------------------------------------
extern "C" void kernel_launch(void* const* d_in, const int* in_sizes, int n_in,
                              void* d_out, int out_size, void* d_ws, size_t ws_size,
                              hipStream_t stream) {
    const float* x  = (const float*)d_in[0];   // (2,16,24,32,32,32)
    const float* gw = (const float*)d_in[1];   // (24,16,16)
    const float* tw = (const float*)d_in[2];   // (16,1,3,3,3)
    const float* gb = (const float*)d_in[3];   // (16)
    const float* tb = (const float*)d_in[4];   // (1)
    float* out = (float*)d_out;
    float* ws  = (float*)d_ws;

    float* wmix = ws;                    // 147456 floats
    float* wt   = ws + 147456;           // 10368 floats
    float* y    = ws + 157824;           // 2*384*32768 floats (16B-aligned offset)

    // 1) build mixed/rotated weight banks
    build_weights<<<dim3(617), dim3(256), 0, stream>>>(gw, tw, wmix, wt);
    // 2) channel-mix GEMM + g_bias
    gemm_mix<<<dim3(PVOL / BN, MCH / BM, 2), dim3(256), 0, stream>>>(wmix, x, gb, y);
    // 3) depthwise conv + t_bias + leaky relu
    dwconv<<<dim3(4, MCH, 2), dim3(256), 0, stream>>>(y, wt, tb, out);
}

// Round 2
// 374.261 us; speedup vs baseline: 1.1721x; 1.1721x over previous
//
#include <hip/hip_runtime.h>
#include <hip/hip_bf16.h>
#include <stdint.h>

typedef unsigned short ushortx;
typedef __attribute__((ext_vector_type(8))) short bs8;   // 8 bf16 (4 VGPRs)
typedef __attribute__((ext_vector_type(4))) float f32x4; // MFMA acc

// ---------------------------------------------------------------------------
// Compile-time octahedral tables (replicates the reference's itertools order)
// ---------------------------------------------------------------------------
struct Tab {
    int shift[24][24];
    int rot[24][27];
};

constexpr Tab make_tab() {
    Tab t{};
    int mats[24][3][3] = {};
    {
        const int perms[6][3] = {{0,1,2},{0,2,1},{1,0,2},{1,2,0},{2,0,1},{2,1,0}};
        const int sgns[8][3]  = {{1,1,1},{1,1,-1},{1,-1,1},{1,-1,-1},
                                 {-1,1,1},{-1,1,-1},{-1,-1,1},{-1,-1,-1}};
        int n = 0;
        for (int pi = 0; pi < 6; ++pi)
            for (int si = 0; si < 8; ++si) {
                int M[3][3] = {};
                for (int i = 0; i < 3; ++i) M[i][perms[pi][i]] = sgns[si][i];
                int det = M[0][0]*(M[1][1]*M[2][2]-M[1][2]*M[2][1])
                        - M[0][1]*(M[1][0]*M[2][2]-M[1][2]*M[2][0])
                        + M[0][2]*(M[1][0]*M[2][1]-M[1][1]*M[2][0]);
                if (det == 1) {
                    for (int i = 0; i < 3; ++i)
                        for (int j = 0; j < 3; ++j) mats[n][i][j] = M[i][j];
                    ++n;
                }
            }
    }
    for (int g = 0; g < 24; ++g)
        for (int h = 0; h < 24; ++h) {
            int P[3][3] = {};
            for (int i = 0; i < 3; ++i)
                for (int j = 0; j < 3; ++j) {
                    int s = 0;
                    for (int e = 0; e < 3; ++e) s += mats[g][e][i] * mats[h][e][j];
                    P[i][j] = s;
                }
            for (int k = 0; k < 24; ++k) {
                bool eq = true;
                for (int i = 0; i < 3; ++i)
                    for (int j = 0; j < 3; ++j)
                        if (mats[k][i][j] != P[i][j]) eq = false;
                if (eq) t.shift[g][h] = k;
            }
        }
    for (int g = 0; g < 24; ++g)
        for (int j = 0; j < 27; ++j) {
            int co[3] = { j/9 - 1, (j/3)%3 - 1, j%3 - 1 };
            int src[3] = {};
            for (int d = 0; d < 3; ++d) {
                int s = 0;
                for (int e = 0; e < 3; ++e) s += co[e] * mats[g][e][d];
                src[d] = s + 1;
            }
            t.rot[g][j] = src[0]*9 + src[1]*3 + src[2];
        }
    return t;
}

__constant__ Tab TAB = make_tab();

#define GG 24
#define OO 16
#define II 16
#define PVOL 32768
#define MCH 384
#define KCH 384
#define K3  1152            // 3*KCH: (Whi*Xhi, Whi*Xlo, Wlo*Xhi) packed along K

// bf16 helpers (RNE)
__device__ __forceinline__ ushortx f2bf(float f) {
    union { float f; unsigned u; } a; a.f = f;
    unsigned r = a.u + 0x7FFFu + ((a.u >> 16) & 1u);
    return (ushortx)(r >> 16);
}
__device__ __forceinline__ float bf2f(ushortx h) {
    union { unsigned u; float f; } a; a.u = ((unsigned)h) << 16;
    return a.f;
}

#define GLOAD16(gp, lp) \
    __builtin_amdgcn_global_load_lds((const __attribute__((address_space(1))) void*)(gp), \
                                     (__attribute__((address_space(3))) void*)(lp), 16, 0, 0)

// ---------------------------------------------------------------------------
// build_weights3: W3 bf16 [384][1152] = (hi,hi,lo) triples, + wt fp32 [384][27]
// ---------------------------------------------------------------------------
__global__ void build_weights3(const float* __restrict__ gw, const float* __restrict__ tw,
                               ushortx* __restrict__ w3, float* __restrict__ wt) {
    int idx = blockIdx.x * 256 + threadIdx.x;
    if (idx < MCH * KCH) {
        int m = idx / KCH, k = idx % KCH;
        int o = m / GG, z = m % GG;
        int i = k / GG, g = k % GG;
        float w = gw[TAB.shift[z][g] * (OO * II) + o * II + i];
        ushortx h = f2bf(w);
        ushortx l = f2bf(w - bf2f(h));
        ushortx* p = w3 + (size_t)m * K3 + 3 * k;
        p[0] = h; p[1] = h; p[2] = l;
    } else {
        int r = idx - MCH * KCH;
        if (r < MCH * 27) {
            int c = r / 27, j = r % 27;
            wt[r] = tw[(c / GG) * 27 + TAB.rot[c % GG][j]];
        }
    }
}

// legacy fp32 weight build (fallback path)
__global__ void build_weights(const float* __restrict__ gw, const float* __restrict__ tw,
                              float* __restrict__ wmix, float* __restrict__ wt) {
    int idx = blockIdx.x * 256 + threadIdx.x;
    if (idx < MCH * KCH) {
        int c = idx / KCH, k = idx % KCH;
        int o = c / GG, z = c % GG;
        int i = k / GG, g = k % GG;
        wmix[idx] = gw[TAB.shift[z][g] * (OO * II) + o * II + i];
    } else {
        int r = idx - MCH * KCH;
        if (r < MCH * 27) {
            int c = r / 27, j = r % 27;
            wt[r] = tw[(c / GG) * 27 + TAB.rot[c % GG][j]];
        }
    }
}

// ---------------------------------------------------------------------------
// convert_x: X[b][k][n] fp32 -> X3t[b][n][k3] bf16 triples (hi, lo, hi)
//   64k x 64n LDS-transposed tiles; coalesced reads, 96B-contig writes
// ---------------------------------------------------------------------------
__global__ __launch_bounds__(256) void convert_x(const float* __restrict__ X,
                                                 ushortx* __restrict__ X3) {
    const int n0 = blockIdx.x * 64, kb = blockIdx.y * 64, b = blockIdx.z;
    __shared__ float s[64][65];
    const int t = threadIdx.x;
    const float* Xb = X + ((size_t)b * KCH + kb) * PVOL;
    {
        int n = t & 63, kbase = t >> 6;
        #pragma unroll
        for (int i = 0; i < 16; ++i) {
            int k = kbase + i * 4;
            s[k][n] = Xb[(size_t)k * PVOL + n0 + n];
        }
    }
    __syncthreads();
    const int n = t >> 2, kq = t & 3;
    union { ushortx u[48]; float4 v[6]; } P;
    #pragma unroll
    for (int j = 0; j < 16; ++j) {
        float f = s[kq * 16 + j][n];
        ushortx h = f2bf(f);
        ushortx l = f2bf(f - bf2f(h));
        P.u[3*j] = h; P.u[3*j+1] = l; P.u[3*j+2] = h;
    }
    float4* dst = (float4*)(X3 + ((size_t)(b * PVOL + n0 + n) * K3 + 3 * (kb + kq * 16)));
    #pragma unroll
    for (int i = 0; i < 6; ++i) dst[i] = P.v[i];
}

// ---------------------------------------------------------------------------
// gemm_mfma: Y[b][m][n] = sum_k3 W3[m][k3]*X3t[b][n][k3] + g_bias[m/24]
//   128x128 tile, BK=64, 4 waves (2x2 of 64x64), 16x16x32 bf16 MFMA,
//   global_load_lds w=16, both-sides XOR swizzle (rule #21).
// ---------------------------------------------------------------------------
__global__ __launch_bounds__(256) void gemm_mfma(const ushortx* __restrict__ W3,
                                                 const ushortx* __restrict__ X3,
                                                 const float* __restrict__ gbias,
                                                 float* __restrict__ Y) {
    __shared__ ushortx As[8192];   // [128 rows][64 k] bf16, 128B rows, swizzled
    __shared__ ushortx Bs[8192];
    const int b = blockIdx.z, m0 = blockIdx.y * 128, n0 = blockIdx.x * 128;
    const int tid = threadIdx.x, lane = tid & 63, wave = tid >> 6;
    const int wr = wave >> 1, wc = wave & 1;
    const int l15 = lane & 15, lq = lane >> 4;

    f32x4 acc[4][4] = {};

    const char* Ab = (const char*)W3 + (size_t)m0 * 2304;
    const char* Bb = (const char*)X3 + ((size_t)(b * PVOL + n0)) * 2304;

    for (int k0b = 0; k0b < 2304; k0b += 128) {
        #pragma unroll
        for (int j = 0; j < 4; ++j) {
            int inst = j * 4 + wave;
            int fb = inst * 1024 + (lane << 4);
            int row = fb >> 7, colb = fb & 127;
            int scol = colb ^ ((row & 7) << 4);     // pre-swizzled source
            GLOAD16(Ab + (size_t)row * 2304 + k0b + scol, (char*)As + fb);
            GLOAD16(Bb + (size_t)row * 2304 + k0b + scol, (char*)Bs + fb);
        }
        __syncthreads();
        #pragma unroll
        for (int kc = 0; kc < 2; ++kc) {
            bs8 a[4], bb[4];
            #pragma unroll
            for (int f = 0; f < 4; ++f) {
                int rowA = wr * 64 + f * 16 + l15;
                int ca = (kc * 64 + lq * 16) ^ ((rowA & 7) << 4);   // swizzled read
                a[f] = *(const bs8*)((const char*)As + rowA * 128 + ca);
                int rowB = wc * 64 + f * 16 + l15;
                int cb = (kc * 64 + lq * 16) ^ ((rowB & 7) << 4);
                bb[f] = *(const bs8*)((const char*)Bs + rowB * 128 + cb);
            }
            #pragma unroll
            for (int fm = 0; fm < 4; ++fm)
                #pragma unroll
                for (int fn = 0; fn < 4; ++fn)
                    acc[fm][fn] = __builtin_amdgcn_mfma_f32_16x16x32_bf16(a[fm], bb[fn], acc[fm][fn], 0, 0, 0);
        }
        __syncthreads();
    }

    float* Yp = Y + (size_t)b * MCH * PVOL;
    #pragma unroll
    for (int fm = 0; fm < 4; ++fm)
        #pragma unroll
        for (int j = 0; j < 4; ++j) {
            int m = m0 + wr * 64 + fm * 16 + lq * 4 + j;
            float bias = gbias[m / GG];
            #pragma unroll
            for (int fn = 0; fn < 4; ++fn) {
                int n = n0 + wc * 64 + fn * 16 + l15;
                Yp[(size_t)m * PVOL + n] = acc[fm][fn][j] + bias;
            }
        }
}

// ---------------------------------------------------------------------------
// Fallback fp32 SGEMM (previous round's kernel, unchanged)
// ---------------------------------------------------------------------------
#define BM 128
#define BN 128
#define BK 16

__global__ __launch_bounds__(256) void gemm_mix(const float* __restrict__ A,
                                                const float* __restrict__ X,
                                                const float* __restrict__ gbias,
                                                float* __restrict__ Y) {
    const int b  = blockIdx.z;
    const int m0 = blockIdx.y * BM;
    const int n0 = blockIdx.x * BN;
    const float* __restrict__ Bp = X + (size_t)b * KCH * PVOL;
    float* __restrict__ Yp = Y + (size_t)b * MCH * PVOL;

    __shared__ float Ash[BK][BM];
    __shared__ float Bsh[BK][BN];

    const int tid = threadIdx.x;
    const int tx = tid % 16;
    const int ty = tid / 16;

    float acc[8][8] = {};

    for (int k0 = 0; k0 < KCH; k0 += BK) {
        #pragma unroll
        for (int r = 0; r < 2; ++r) {
            int t = tid + r * 256;
            int m = t / 4;
            int kk = (t % 4) * 4;
            float4 v = *(const float4*)&A[(m0 + m) * KCH + k0 + kk];
            Ash[kk + 0][m] = v.x; Ash[kk + 1][m] = v.y;
            Ash[kk + 2][m] = v.z; Ash[kk + 3][m] = v.w;
        }
        #pragma unroll
        for (int r = 0; r < 2; ++r) {
            int t = tid + r * 256;
            int kk = t / 32;
            int n = (t % 32) * 4;
            *(float4*)&Bsh[kk][n] = *(const float4*)&Bp[(size_t)(k0 + kk) * PVOL + n0 + n];
        }
        __syncthreads();
        #pragma unroll
        for (int kk = 0; kk < BK; ++kk) {
            float af[8], bf[8];
            #pragma unroll
            for (int i = 0; i < 4; ++i) {
                af[i]     = Ash[kk][ty * 4 + i];
                af[4 + i] = Ash[kk][64 + ty * 4 + i];
                bf[i]     = Bsh[kk][tx * 4 + i];
                bf[4 + i] = Bsh[kk][64 + tx * 4 + i];
            }
            #pragma unroll
            for (int i = 0; i < 8; ++i)
                #pragma unroll
                for (int j = 0; j < 8; ++j)
                    acc[i][j] += af[i] * bf[j];
        }
        __syncthreads();
    }

    #pragma unroll
    for (int i = 0; i < 8; ++i) {
        int m = m0 + ((i < 4) ? (ty * 4 + i) : (64 + ty * 4 + (i - 4)));
        float bias = gbias[m / GG];
        float4 v0 = { acc[i][0] + bias, acc[i][1] + bias, acc[i][2] + bias, acc[i][3] + bias };
        float4 v1 = { acc[i][4] + bias, acc[i][5] + bias, acc[i][6] + bias, acc[i][7] + bias };
        *(float4*)&Yp[(size_t)m * PVOL + n0 + tx * 4]      = v0;
        *(float4*)&Yp[(size_t)m * PVOL + n0 + 64 + tx * 4] = v1;
    }
}

// ---------------------------------------------------------------------------
// dwconv: depthwise 3x3x3 + t_bias + leaky_relu. x-slab 4 (was 8): LDS 27.7KB
// -> ~5 blocks/CU; 3 split accumulators break the 27-deep FMA chain.
// ---------------------------------------------------------------------------
__global__ __launch_bounds__(256) void dwconv(const float* __restrict__ Y,
                                              const float* __restrict__ Wt,
                                              const float* __restrict__ tb,
                                              float* __restrict__ O) {
    const int x0 = blockIdx.x * 4;
    const int c  = blockIdx.y;
    const int b  = blockIdx.z;
    const float* __restrict__ Yc = Y + ((size_t)(b * MCH + c)) * PVOL;
    float* __restrict__ Oc = O + ((size_t)(b * MCH + c)) * PVOL;

    __shared__ float s[6][34][34];
    __shared__ float taps[27];
    const int tid = threadIdx.x;

    for (int i = tid; i < 6 * 34 * 34; i += 256) ((float*)s)[i] = 0.f;
    if (tid < 27) taps[tid] = Wt[c * 27 + tid];
    __syncthreads();

    {
        int yy = tid / 8;
        int zz = (tid % 8) * 4;
        #pragma unroll
        for (int lx = 0; lx < 6; ++lx) {
            int x = x0 - 1 + lx;
            if (x < 0 || x >= 32) continue;
            float4 v = *(const float4*)&Yc[x * 1024 + yy * 32 + zz];
            s[lx][1 + yy][1 + zz + 0] = v.x;
            s[lx][1 + yy][1 + zz + 1] = v.y;
            s[lx][1 + yy][1 + zz + 2] = v.z;
            s[lx][1 + yy][1 + zz + 3] = v.w;
        }
    }
    __syncthreads();

    const float t0 = tb[0];
    float w[27];
    #pragma unroll
    for (int j = 0; j < 27; ++j) w[j] = taps[j];

    const int z = tid % 32;
    const int ybase = tid / 32;

    for (int yi = 0; yi < 4; ++yi) {
        const int y = ybase + yi * 8;
        float p0[9], p1[9], p2[9];
        #pragma unroll
        for (int dy = 0; dy < 3; ++dy)
            #pragma unroll
            for (int dz = 0; dz < 3; ++dz) {
                p0[dy * 3 + dz] = s[0][y + dy][z + dz];
                p1[dy * 3 + dz] = s[1][y + dy][z + dz];
            }
        #pragma unroll
        for (int xi = 0; xi < 4; ++xi) {
            #pragma unroll
            for (int q = 0; q < 9; ++q) p2[q] = s[xi + 2][y + (q / 3)][z + (q % 3)];
            float a0 = 0.f, a1 = 0.f, a2 = 0.f;
            #pragma unroll
            for (int q = 0; q < 9; ++q) {
                a0 += p0[q] * w[q];
                a1 += p1[q] * w[9 + q];
                a2 += p2[q] * w[18 + q];
            }
            #pragma unroll
            for (int q = 0; q < 9; ++q) { p0[q] = p1[q]; p1[q] = p2[q]; }
            float v = a0 + a1 + a2 + t0;
            Oc[(x0 + xi) * 1024 + y * 32 + z] = (v > 0.f) ? v : 0.01f * v;
        }
    }
}

// ---------------------------------------------------------------------------
extern "C" void kernel_launch(void* const* d_in, const int* in_sizes, int n_in,
                              void* d_out, int out_size, void* d_ws, size_t ws_size,
                              hipStream_t stream) {
    const float* x  = (const float*)d_in[0];
    const float* gw = (const float*)d_in[1];
    const float* tw = (const float*)d_in[2];
    const float* gb = (const float*)d_in[3];
    const float* tb = (const float*)d_in[4];
    float* out = (float*)d_out;
    float* ws  = (float*)d_ws;

    // layout (float offsets):
    //   wt   : 0        .. 10368
    //   W3   : 10368    (bf16, 442368 ushorts = 221184 floats)   [mfma path]
    //   wmix : 10368    (fp32, 147456 floats)                    [fallback]
    //   Y    : 231552   .. +25165824
    //   X3t  : 25397376 (bf16, 75497472 ushorts = 37748736 floats)
    float*   wt   = ws;
    ushortx* w3   = (ushortx*)(ws + 10368);
    float*   wmix = ws + 10368;
    float*   y    = ws + 231552;
    ushortx* x3   = (ushortx*)(ws + 25397376);

    const size_t need = (size_t)(25397376 + 37748736) * 4;  // ~253 MB

    if (ws_size >= need) {
        build_weights3<<<dim3(617), dim3(256), 0, stream>>>(gw, tw, w3, wt);
        convert_x<<<dim3(512, 6, 2), dim3(256), 0, stream>>>(x, x3);
        gemm_mfma<<<dim3(256, 3, 2), dim3(256), 0, stream>>>(w3, x3, gb, y);
    } else {
        build_weights<<<dim3(617), dim3(256), 0, stream>>>(gw, tw, wmix, wt);
        gemm_mix<<<dim3(PVOL / BN, MCH / BM, 2), dim3(256), 0, stream>>>(wmix, x, gb, y);
    }
    dwconv<<<dim3(8, MCH, 2), dim3(256), 0, stream>>>(y, wt, tb, out);
}

// Round 4
// 373.663 us; speedup vs baseline: 1.1740x; 1.0016x over previous
//
#include <hip/hip_runtime.h>
#include <hip/hip_bf16.h>
#include <stdint.h>

typedef unsigned short ushortx;
typedef __attribute__((ext_vector_type(8))) short bs8;   // 8 bf16 (4 VGPRs)
typedef __attribute__((ext_vector_type(4))) float f32x4; // MFMA acc

// ---------------------------------------------------------------------------
// Compile-time octahedral tables (replicates the reference's itertools order)
// ---------------------------------------------------------------------------
struct Tab {
    int shift[24][24];
    int rot[24][27];
};

constexpr Tab make_tab() {
    Tab t{};
    int mats[24][3][3] = {};
    {
        const int perms[6][3] = {{0,1,2},{0,2,1},{1,0,2},{1,2,0},{2,0,1},{2,1,0}};
        const int sgns[8][3]  = {{1,1,1},{1,1,-1},{1,-1,1},{1,-1,-1},
                                 {-1,1,1},{-1,1,-1},{-1,-1,1},{-1,-1,-1}};
        int n = 0;
        for (int pi = 0; pi < 6; ++pi)
            for (int si = 0; si < 8; ++si) {
                int M[3][3] = {};
                for (int i = 0; i < 3; ++i) M[i][perms[pi][i]] = sgns[si][i];
                int det = M[0][0]*(M[1][1]*M[2][2]-M[1][2]*M[2][1])
                        - M[0][1]*(M[1][0]*M[2][2]-M[1][2]*M[2][0])
                        + M[0][2]*(M[1][0]*M[2][1]-M[1][1]*M[2][0]);
                if (det == 1) {
                    for (int i = 0; i < 3; ++i)
                        for (int j = 0; j < 3; ++j) mats[n][i][j] = M[i][j];
                    ++n;
                }
            }
    }
    for (int g = 0; g < 24; ++g)
        for (int h = 0; h < 24; ++h) {
            int P[3][3] = {};
            for (int i = 0; i < 3; ++i)
                for (int j = 0; j < 3; ++j) {
                    int s = 0;
                    for (int e = 0; e < 3; ++e) s += mats[g][e][i] * mats[h][e][j];
                    P[i][j] = s;
                }
            for (int k = 0; k < 24; ++k) {
                bool eq = true;
                for (int i = 0; i < 3; ++i)
                    for (int j = 0; j < 3; ++j)
                        if (mats[k][i][j] != P[i][j]) eq = false;
                if (eq) t.shift[g][h] = k;
            }
        }
    for (int g = 0; g < 24; ++g)
        for (int j = 0; j < 27; ++j) {
            int co[3] = { j/9 - 1, (j/3)%3 - 1, j%3 - 1 };
            int src[3] = {};
            for (int d = 0; d < 3; ++d) {
                int s = 0;
                for (int e = 0; e < 3; ++e) s += co[e] * mats[g][e][d];
                src[d] = s + 1;
            }
            t.rot[g][j] = src[0]*9 + src[1]*3 + src[2];
        }
    return t;
}

__constant__ Tab TAB = make_tab();

#define GG 24
#define OO 16
#define II 16
#define PVOL 32768
#define MCH 384
#define KCH 384
#define K3  1152            // 3*KCH: (Whi*Xhi, Whi*Xlo, Wlo*Xhi) packed along K

// bf16 helpers (RNE)
__device__ __forceinline__ ushortx f2bf(float f) {
    union { float f; unsigned u; } a; a.f = f;
    unsigned r = a.u + 0x7FFFu + ((a.u >> 16) & 1u);
    return (ushortx)(r >> 16);
}
__device__ __forceinline__ float bf2f(ushortx h) {
    union { unsigned u; float f; } a; a.u = ((unsigned)h) << 16;
    return a.f;
}

#define GLOAD16(gp, lp) \
    __builtin_amdgcn_global_load_lds((const __attribute__((address_space(1))) void*)(gp), \
                                     (__attribute__((address_space(3))) void*)(lp), 16, 0, 0)

// ---------------------------------------------------------------------------
// build_weights3: W3 bf16 [384][1152] = (hi,hi,lo) triples, + wt fp32 [384][27]
// ---------------------------------------------------------------------------
__global__ void build_weights3(const float* __restrict__ gw, const float* __restrict__ tw,
                               ushortx* __restrict__ w3, float* __restrict__ wt) {
    int idx = blockIdx.x * 256 + threadIdx.x;
    if (idx < MCH * KCH) {
        int m = idx / KCH, k = idx % KCH;
        int o = m / GG, z = m % GG;
        int i = k / GG, g = k % GG;
        float w = gw[TAB.shift[z][g] * (OO * II) + o * II + i];
        ushortx h = f2bf(w);
        ushortx l = f2bf(w - bf2f(h));
        ushortx* p = w3 + (size_t)m * K3 + 3 * k;
        p[0] = h; p[1] = h; p[2] = l;
    } else {
        int r = idx - MCH * KCH;
        if (r < MCH * 27) {
            int c = r / 27, j = r % 27;
            wt[r] = tw[(c / GG) * 27 + TAB.rot[c % GG][j]];
        }
    }
}

// ---------------------------------------------------------------------------
// convert_x v2: X[b][k][n] fp32 -> X3t[b][n][k3] bf16 triples (hi, lo, hi)
//   Tile 64k x 128n. Register-staged float4 loads (8 in flight — fixes the
//   VGPR=20 latency serialization seen in R2), LDS [64][132] transpose,
//   12 independent float4 stores per thread (384B-contiguous runs per n-row).
// ---------------------------------------------------------------------------
__global__ __launch_bounds__(256) void convert_x(const float* __restrict__ X,
                                                 ushortx* __restrict__ X3) {
    const int n0 = blockIdx.x * 128, kb = blockIdx.y * 64, b = blockIdx.z;
    __shared__ float s[64][132];
    const int t = threadIdx.x;
    const float* Xb = X + ((size_t)b * KCH + kb) * PVOL;

    // phase 1: 8 float4 loads per thread, all independent, then LDS writes
    {
        const int krow = t >> 5;          // 0..7
        const int ncol = (t & 31) * 4;    // 0..124
        float4 r[8];
        #pragma unroll
        for (int p = 0; p < 8; ++p)
            r[p] = *(const float4*)&Xb[(size_t)(krow + p * 8) * PVOL + n0 + ncol];
        #pragma unroll
        for (int p = 0; p < 8; ++p)
            *(float4*)&s[krow + p * 8][ncol] = r[p];
    }
    __syncthreads();

    // phase 2: transpose-read 32 k for one n, convert, pack triples, store
    const int nl = t >> 1;        // 0..127
    const int kh = t & 1;         // 0..1 (32-k half)
    float fv[32];
    #pragma unroll
    for (int j = 0; j < 32; ++j) fv[j] = s[kh * 32 + j][nl];

    union { ushortx u[96]; float4 v[12]; } P;
    #pragma unroll
    for (int j = 0; j < 32; ++j) {
        float f = fv[j];
        ushortx h = f2bf(f);
        ushortx l = f2bf(f - bf2f(h));
        P.u[3*j] = h; P.u[3*j+1] = l; P.u[3*j+2] = h;   // (h,l,h): must match W(h,h,l)
    }
    float4* dst = (float4*)(X3 + ((size_t)(b * PVOL + n0 + nl) * K3 + 3 * (kb + kh * 32)));
    #pragma unroll
    for (int i = 0; i < 12; ++i) dst[i] = P.v[i];
}

// ---------------------------------------------------------------------------
// gemm_mfma: unchanged from R2 (proven: absmax 0.125 pass, ~90 us)
// ---------------------------------------------------------------------------
__global__ __launch_bounds__(256) void gemm_mfma(const ushortx* __restrict__ W3,
                                                 const ushortx* __restrict__ X3,
                                                 const float* __restrict__ gbias,
                                                 float* __restrict__ Y) {
    __shared__ ushortx As[8192];   // [128 rows][64 k] bf16, 128B rows, swizzled
    __shared__ ushortx Bs[8192];
    const int b = blockIdx.z, m0 = blockIdx.y * 128, n0 = blockIdx.x * 128;
    const int tid = threadIdx.x, lane = tid & 63, wave = tid >> 6;
    const int wr = wave >> 1, wc = wave & 1;
    const int l15 = lane & 15, lq = lane >> 4;

    f32x4 acc[4][4] = {};

    const char* Ab = (const char*)W3 + (size_t)m0 * 2304;
    const char* Bb = (const char*)X3 + ((size_t)(b * PVOL + n0)) * 2304;

    for (int k0b = 0; k0b < 2304; k0b += 128) {
        #pragma unroll
        for (int j = 0; j < 4; ++j) {
            int inst = j * 4 + wave;
            int fb = inst * 1024 + (lane << 4);
            int row = fb >> 7, colb = fb & 127;
            int scol = colb ^ ((row & 7) << 4);     // pre-swizzled source
            GLOAD16(Ab + (size_t)row * 2304 + k0b + scol, (char*)As + fb);
            GLOAD16(Bb + (size_t)row * 2304 + k0b + scol, (char*)Bs + fb);
        }
        __syncthreads();
        #pragma unroll
        for (int kc = 0; kc < 2; ++kc) {
            bs8 a[4], bb[4];
            #pragma unroll
            for (int f = 0; f < 4; ++f) {
                int rowA = wr * 64 + f * 16 + l15;
                int ca = (kc * 64 + lq * 16) ^ ((rowA & 7) << 4);   // swizzled read
                a[f] = *(const bs8*)((const char*)As + rowA * 128 + ca);
                int rowB = wc * 64 + f * 16 + l15;
                int cb = (kc * 64 + lq * 16) ^ ((rowB & 7) << 4);
                bb[f] = *(const bs8*)((const char*)Bs + rowB * 128 + cb);
            }
            #pragma unroll
            for (int fm = 0; fm < 4; ++fm)
                #pragma unroll
                for (int fn = 0; fn < 4; ++fn)
                    acc[fm][fn] = __builtin_amdgcn_mfma_f32_16x16x32_bf16(a[fm], bb[fn], acc[fm][fn], 0, 0, 0);
        }
        __syncthreads();
    }

    float* Yp = Y + (size_t)b * MCH * PVOL;
    #pragma unroll
    for (int fm = 0; fm < 4; ++fm)
        #pragma unroll
        for (int j = 0; j < 4; ++j) {
            int m = m0 + wr * 64 + fm * 16 + lq * 4 + j;
            float bias = gbias[m / GG];
            #pragma unroll
            for (int fn = 0; fn < 4; ++fn) {
                int n = n0 + wc * 64 + fn * 16 + l15;
                Yp[(size_t)m * PVOL + n] = acc[fm][fn][j] + bias;
            }
        }
}

// ---------------------------------------------------------------------------
// dwconv v2: depthwise 3x3x3 + t_bias + leaky_relu, z-vectorized (float4).
//   Block = (x-slab of 4, channel, batch); 256 thr cover a full 32x32 yz plane
//   per x-step. LDS [6][34][40], data at col 4+z so ds writes AND the 3
//   b128-per-row reads are 16B aligned. x-window slides in registers
//   (fully-unrolled static (xi%3) indexing).
// ---------------------------------------------------------------------------
__global__ __launch_bounds__(256) void dwconv(const float* __restrict__ Y,
                                              const float* __restrict__ Wt,
                                              const float* __restrict__ tb,
                                              float* __restrict__ O) {
    const int x0 = blockIdx.x * 4;
    const int c  = blockIdx.y;
    const int b  = blockIdx.z;
    const float* __restrict__ Yc = Y + ((size_t)(b * MCH + c)) * PVOL;
    float* __restrict__ Oc = O + ((size_t)(b * MCH + c)) * PVOL;

    __shared__ float s[6][34][40];   // [x-local][1+y][4+z], halos zero
    __shared__ float taps[27];
    const int t = threadIdx.x;

    // zero LDS (float4): 6*34*40/4 = 2040 vecs
    {
        float4 z4 = {0.f, 0.f, 0.f, 0.f};
        float4* sp = (float4*)s;
        for (int i = t; i < 2040; i += 256) sp[i] = z4;
    }
    if (t < 27) taps[t] = Wt[c * 27 + t];
    __syncthreads();

    const int y  = t >> 3;          // 0..31
    const int z0 = (t & 7) * 4;     // 0,4,..,28

    // load 6 x-planes, register-staged for MLP
    {
        float4 r[6];
        bool ok[6];
        #pragma unroll
        for (int lx = 0; lx < 6; ++lx) {
            int x = x0 - 1 + lx;
            ok[lx] = (x >= 0 && x < 32);
            r[lx] = ok[lx] ? *(const float4*)&Yc[(size_t)x * 1024 + y * 32 + z0]
                           : (float4){0.f, 0.f, 0.f, 0.f};
        }
        #pragma unroll
        for (int lx = 0; lx < 6; ++lx)
            *(float4*)&s[lx][1 + y][4 + z0] = r[lx];
    }
    __syncthreads();

    const float t0 = tb[0];
    float w[27];
    #pragma unroll
    for (int j = 0; j < 27; ++j) w[j] = taps[j];

    // window register file: Wn[slot][row dy][6 z-vals (z0-1..z0+4)]
    float Wn[3][3][6];

    // helper pattern: load 12 floats of (plane, row), keep window [3..8]
    #define LOADWIN(slot, plane)                                              \
        {                                                                     \
            _Pragma("unroll")                                                 \
            for (int dy = 0; dy < 3; ++dy) {                                  \
                float4 a = *(const float4*)&s[plane][y + dy][z0];             \
                float4 bq = *(const float4*)&s[plane][y + dy][z0 + 4];        \
                float4 cq = *(const float4*)&s[plane][y + dy][z0 + 8];        \
                Wn[slot][dy][0] = a.w;                                        \
                Wn[slot][dy][1] = bq.x; Wn[slot][dy][2] = bq.y;               \
                Wn[slot][dy][3] = bq.z; Wn[slot][dy][4] = bq.w;               \
                Wn[slot][dy][5] = cq.x;                                       \
            }                                                                 \
        }

    LOADWIN(0, 0)
    LOADWIN(1, 1)

    #pragma unroll
    for (int xi = 0; xi < 4; ++xi) {
        LOADWIN((xi + 2) % 3, (xi + 2))
        const int s0 = xi % 3, s1 = (xi + 1) % 3, s2 = (xi + 2) % 3;
        float4 o;
        #pragma unroll
        for (int zz = 0; zz < 4; ++zz) {
            float a0 = 0.f, a1 = 0.f, a2 = 0.f;
            #pragma unroll
            for (int dy = 0; dy < 3; ++dy)
                #pragma unroll
                for (int dc = 0; dc < 3; ++dc) {
                    a0 += Wn[s0][dy][zz + dc] * w[dy * 3 + dc];
                    a1 += Wn[s1][dy][zz + dc] * w[9 + dy * 3 + dc];
                    a2 += Wn[s2][dy][zz + dc] * w[18 + dy * 3 + dc];
                }
            float v = a0 + a1 + a2 + t0;
            o[zz] = (v > 0.f) ? v : 0.01f * v;
        }
        *(float4*)&Oc[(size_t)(x0 + xi) * 1024 + y * 32 + z0] = o;
    }
    #undef LOADWIN
}

// ---------------------------------------------------------------------------
// Fallback fp32 path (unchanged)
// ---------------------------------------------------------------------------
__global__ void build_weights(const float* __restrict__ gw, const float* __restrict__ tw,
                              float* __restrict__ wmix, float* __restrict__ wt) {
    int idx = blockIdx.x * 256 + threadIdx.x;
    if (idx < MCH * KCH) {
        int c = idx / KCH, k = idx % KCH;
        int o = c / GG, z = c % GG;
        int i = k / GG, g = k % GG;
        wmix[idx] = gw[TAB.shift[z][g] * (OO * II) + o * II + i];
    } else {
        int r = idx - MCH * KCH;
        if (r < MCH * 27) {
            int c = r / 27, j = r % 27;
            wt[r] = tw[(c / GG) * 27 + TAB.rot[c % GG][j]];
        }
    }
}

#define BM 128
#define BN 128
#define BK 16

__global__ __launch_bounds__(256) void gemm_mix(const float* __restrict__ A,
                                                const float* __restrict__ X,
                                                const float* __restrict__ gbias,
                                                float* __restrict__ Y) {
    const int b  = blockIdx.z;
    const int m0 = blockIdx.y * BM;
    const int n0 = blockIdx.x * BN;
    const float* __restrict__ Bp = X + (size_t)b * KCH * PVOL;
    float* __restrict__ Yp = Y + (size_t)b * MCH * PVOL;

    __shared__ float Ash[BK][BM];
    __shared__ float Bsh[BK][BN];

    const int tid = threadIdx.x;
    const int tx = tid % 16;
    const int ty = tid / 16;

    float acc[8][8] = {};

    for (int k0 = 0; k0 < KCH; k0 += BK) {
        #pragma unroll
        for (int r = 0; r < 2; ++r) {
            int tt = tid + r * 256;
            int m = tt / 4;
            int kk = (tt % 4) * 4;
            float4 v = *(const float4*)&A[(m0 + m) * KCH + k0 + kk];
            Ash[kk + 0][m] = v.x; Ash[kk + 1][m] = v.y;
            Ash[kk + 2][m] = v.z; Ash[kk + 3][m] = v.w;
        }
        #pragma unroll
        for (int r = 0; r < 2; ++r) {
            int tt = tid + r * 256;
            int kk = tt / 32;
            int n = (tt % 32) * 4;
            *(float4*)&Bsh[kk][n] = *(const float4*)&Bp[(size_t)(k0 + kk) * PVOL + n0 + n];
        }
        __syncthreads();
        #pragma unroll
        for (int kk = 0; kk < BK; ++kk) {
            float af[8], bf[8];
            #pragma unroll
            for (int i = 0; i < 4; ++i) {
                af[i]     = Ash[kk][ty * 4 + i];
                af[4 + i] = Ash[kk][64 + ty * 4 + i];
                bf[i]     = Bsh[kk][tx * 4 + i];
                bf[4 + i] = Bsh[kk][64 + tx * 4 + i];
            }
            #pragma unroll
            for (int i = 0; i < 8; ++i)
                #pragma unroll
                for (int j = 0; j < 8; ++j)
                    acc[i][j] += af[i] * bf[j];
        }
        __syncthreads();
    }

    #pragma unroll
    for (int i = 0; i < 8; ++i) {
        int m = m0 + ((i < 4) ? (ty * 4 + i) : (64 + ty * 4 + (i - 4)));
        float bias = gbias[m / GG];
        float4 v0 = { acc[i][0] + bias, acc[i][1] + bias, acc[i][2] + bias, acc[i][3] + bias };
        float4 v1 = { acc[i][4] + bias, acc[i][5] + bias, acc[i][6] + bias, acc[i][7] + bias };
        *(float4*)&Yp[(size_t)m * PVOL + n0 + tx * 4]      = v0;
        *(float4*)&Yp[(size_t)m * PVOL + n0 + 64 + tx * 4] = v1;
    }
}

// ---------------------------------------------------------------------------
extern "C" void kernel_launch(void* const* d_in, const int* in_sizes, int n_in,
                              void* d_out, int out_size, void* d_ws, size_t ws_size,
                              hipStream_t stream) {
    const float* x  = (const float*)d_in[0];
    const float* gw = (const float*)d_in[1];
    const float* tw = (const float*)d_in[2];
    const float* gb = (const float*)d_in[3];
    const float* tb = (const float*)d_in[4];
    float* out = (float*)d_out;
    float* ws  = (float*)d_ws;

    float*   wt   = ws;
    ushortx* w3   = (ushortx*)(ws + 10368);
    float*   wmix = ws + 10368;
    float*   y    = ws + 231552;
    ushortx* x3   = (ushortx*)(ws + 25397376);

    const size_t need = (size_t)(25397376 + 37748736) * 4;  // ~253 MB

    if (ws_size >= need) {
        build_weights3<<<dim3(617), dim3(256), 0, stream>>>(gw, tw, w3, wt);
        convert_x<<<dim3(256, 6, 2), dim3(256), 0, stream>>>(x, x3);
        gemm_mfma<<<dim3(256, 3, 2), dim3(256), 0, stream>>>(w3, x3, gb, y);
    } else {
        build_weights<<<dim3(617), dim3(256), 0, stream>>>(gw, tw, wmix, wt);
        gemm_mix<<<dim3(PVOL / BN, MCH / BM, 2), dim3(256), 0, stream>>>(wmix, x, gb, y);
    }
    dwconv<<<dim3(8, MCH, 2), dim3(256), 0, stream>>>(y, wt, tb, out);
}

// Round 6
// 304.595 us; speedup vs baseline: 1.4402x; 1.2268x over previous
//
#include <hip/hip_runtime.h>
#include <hip/hip_bf16.h>
#include <stdint.h>

typedef unsigned short ushortx;
typedef __attribute__((ext_vector_type(8))) short bs8;   // 8 bf16 (4 VGPRs)
typedef __attribute__((ext_vector_type(4))) float f32x4; // MFMA acc

// ---------------------------------------------------------------------------
// Compile-time octahedral tables (replicates the reference's itertools order)
// ---------------------------------------------------------------------------
struct Tab {
    int shift[24][24];
    int rot[24][27];
};

constexpr Tab make_tab() {
    Tab t{};
    int mats[24][3][3] = {};
    {
        const int perms[6][3] = {{0,1,2},{0,2,1},{1,0,2},{1,2,0},{2,0,1},{2,1,0}};
        const int sgns[8][3]  = {{1,1,1},{1,1,-1},{1,-1,1},{1,-1,-1},
                                 {-1,1,1},{-1,1,-1},{-1,-1,1},{-1,-1,-1}};
        int n = 0;
        for (int pi = 0; pi < 6; ++pi)
            for (int si = 0; si < 8; ++si) {
                int M[3][3] = {};
                for (int i = 0; i < 3; ++i) M[i][perms[pi][i]] = sgns[si][i];
                int det = M[0][0]*(M[1][1]*M[2][2]-M[1][2]*M[2][1])
                        - M[0][1]*(M[1][0]*M[2][2]-M[1][2]*M[2][0])
                        + M[0][2]*(M[1][0]*M[2][1]-M[1][1]*M[2][0]);
                if (det == 1) {
                    for (int i = 0; i < 3; ++i)
                        for (int j = 0; j < 3; ++j) mats[n][i][j] = M[i][j];
                    ++n;
                }
            }
    }
    for (int g = 0; g < 24; ++g)
        for (int h = 0; h < 24; ++h) {
            int P[3][3] = {};
            for (int i = 0; i < 3; ++i)
                for (int j = 0; j < 3; ++j) {
                    int s = 0;
                    for (int e = 0; e < 3; ++e) s += mats[g][e][i] * mats[h][e][j];
                    P[i][j] = s;
                }
            for (int k = 0; k < 24; ++k) {
                bool eq = true;
                for (int i = 0; i < 3; ++i)
                    for (int j = 0; j < 3; ++j)
                        if (mats[k][i][j] != P[i][j]) eq = false;
                if (eq) t.shift[g][h] = k;
            }
        }
    for (int g = 0; g < 24; ++g)
        for (int j = 0; j < 27; ++j) {
            int co[3] = { j/9 - 1, (j/3)%3 - 1, j%3 - 1 };
            int src[3] = {};
            for (int d = 0; d < 3; ++d) {
                int s = 0;
                for (int e = 0; e < 3; ++e) s += co[e] * mats[g][e][d];
                src[d] = s + 1;
            }
            t.rot[g][j] = src[0]*9 + src[1]*3 + src[2];
        }
    return t;
}

__constant__ Tab TAB = make_tab();

#define GG 24
#define OO 16
#define II 16
#define PVOL 32768
#define MCH 384
#define KCH 384
#define KG  48      // 384 k / 8 per 16B chunk

// bf16 helpers (RNE)
__device__ __forceinline__ unsigned f2bfu(float f) {
    union { float f; unsigned u; } a; a.f = f;
    unsigned r = a.u + 0x7FFFu + ((a.u >> 16) & 1u);
    return r >> 16;
}
__device__ __forceinline__ float bfu2f(unsigned h) {
    union { unsigned u; float f; } a; a.u = h << 16;
    return a.f;
}

#define GLOAD16(gp, lp) \
    __builtin_amdgcn_global_load_lds((const __attribute__((address_space(1))) void*)(gp), \
                                     (__attribute__((address_space(3))) void*)(lp), 16, 0, 0)

// ---------------------------------------------------------------------------
// build_weights2: W2 bf16 [384 m][768 k2] where each 32-k block of the
// original k is stored as [32 hi | 32 lo]  (row = 1536 B), + wt fp32 [384][27]
// ---------------------------------------------------------------------------
__global__ void build_weights2(const float* __restrict__ gw, const float* __restrict__ tw,
                               ushortx* __restrict__ w2, float* __restrict__ wt) {
    int idx = blockIdx.x * 256 + threadIdx.x;
    if (idx < MCH * KCH) {
        int m = idx / KCH, k = idx % KCH;
        int o = m / GG, z = m % GG;
        int i = k / GG, g = k % GG;
        float w = gw[TAB.shift[z][g] * (OO * II) + o * II + i];
        unsigned h = f2bfu(w);
        unsigned l = f2bfu(w - bfu2f(h));
        size_t base = (size_t)m * 768 + (k >> 5) * 64 + (k & 31);
        w2[base]      = (ushortx)h;
        w2[base + 32] = (ushortx)l;
    } else {
        int r = idx - MCH * KCH;
        if (r < MCH * 27) {
            int c = r / 27, j = r % 27;
            wt[r] = tw[(c / GG) * 27 + TAB.rot[c % GG][j]];
        }
    }
}

// ---------------------------------------------------------------------------
// convert_x v3: X[b][k][n] fp32 -> Xhi/Xlo planes, chunked [b][kg][n][8] bf16.
//   Pure-register uint4 packing (NO union / arrays -> no scratch, the R2/R4
//   104us mystery). Tile = 8k x 256n, LDS 8.3KB transpose, coalesced
//   1024B-contiguous reads AND stores.
// ---------------------------------------------------------------------------
__global__ __launch_bounds__(256) void convert_x(const float* __restrict__ X,
                                                 uint4* __restrict__ Xhi,
                                                 uint4* __restrict__ Xlo) {
    const int n0 = blockIdx.x * 256, kg = blockIdx.y, b = blockIdx.z;
    __shared__ float s[8][260];
    const int t = threadIdx.x;
    const float* Xb = X + ((size_t)b * KCH + kg * 8) * PVOL;

    {
        const int r0 = t >> 6, c4 = (t & 63) * 4;
        float4 v0 = *(const float4*)&Xb[(size_t)r0 * PVOL + n0 + c4];
        float4 v1 = *(const float4*)&Xb[(size_t)(r0 + 4) * PVOL + n0 + c4];
        *(float4*)&s[r0][c4] = v0;
        *(float4*)&s[r0 + 4][c4] = v1;
    }
    __syncthreads();

    const int n = t;
    float f0 = s[0][n], f1 = s[1][n], f2 = s[2][n], f3 = s[3][n];
    float f4 = s[4][n], f5 = s[5][n], f6 = s[6][n], f7 = s[7][n];

    unsigned h0 = f2bfu(f0), h1 = f2bfu(f1), h2 = f2bfu(f2), h3 = f2bfu(f3);
    unsigned h4 = f2bfu(f4), h5 = f2bfu(f5), h6 = f2bfu(f6), h7 = f2bfu(f7);
    uint4 H = { h0 | (h1 << 16), h2 | (h3 << 16), h4 | (h5 << 16), h6 | (h7 << 16) };

    unsigned l0 = f2bfu(f0 - bfu2f(h0)), l1 = f2bfu(f1 - bfu2f(h1));
    unsigned l2 = f2bfu(f2 - bfu2f(h2)), l3 = f2bfu(f3 - bfu2f(h3));
    unsigned l4 = f2bfu(f4 - bfu2f(h4)), l5 = f2bfu(f5 - bfu2f(h5));
    unsigned l6 = f2bfu(f6 - bfu2f(h6)), l7 = f2bfu(f7 - bfu2f(h7));
    uint4 L = { l0 | (l1 << 16), l2 | (l3 << 16), l4 | (l5 << 16), l6 | (l7 << 16) };

    const size_t ci = ((size_t)(b * KG + kg)) * PVOL + n0 + n;   // 16B-chunk index
    Xhi[ci] = H;
    Xlo[ci] = L;
}

// ---------------------------------------------------------------------------
// gemm_mfma v3: Y[b][m][n] = sum_k (Whi+Wlo)(Xhi+Xlo) 3-term split, K=384.
//   128x128 tile, BK=32, LDS rows = [32k hi | 32k lo] = 128 B (A and B),
//   both-sides XOR chunk-swizzle, 3 MFMAs per (fm,fn) sharing hi/lo frags.
//   12 K-iters (was 18), 16 ds_read + 48 MFMA per wave-iter.
// ---------------------------------------------------------------------------
__global__ __launch_bounds__(256) void gemm_mfma(const ushortx* __restrict__ W2,
                                                 const uint4* __restrict__ Xhi,
                                                 const uint4* __restrict__ Xlo,
                                                 const float* __restrict__ gbias,
                                                 float* __restrict__ Y) {
    __shared__ ushortx As[8192];   // [128 m][ hi 64B | lo 64B ] swizzled
    __shared__ ushortx Bs[8192];   // [128 n][ hi 64B | lo 64B ] swizzled
    const int b = blockIdx.z, m0 = blockIdx.y * 128, n0 = blockIdx.x * 128;
    const int tid = threadIdx.x, lane = tid & 63, wave = tid >> 6;
    const int wr = wave >> 1, wc = wave & 1;
    const int l15 = lane & 15, lq = lane >> 4;

    f32x4 acc[4][4] = {};

    const char* Ab = (const char*)W2 + (size_t)m0 * 1536;
    const uint4* XH = Xhi + (size_t)b * KG * PVOL + n0;
    const uint4* XL = Xlo + (size_t)b * KG * PVOL + n0;

    for (int it = 0; it < 12; ++it) {
        #pragma unroll
        for (int j = 0; j < 4; ++j) {
            int inst = j * 4 + wave;
            int fb = inst * 1024 + (lane << 4);     // flat LDS byte offset
            int row = fb >> 7;                      // 0..127
            int slot = (fb >> 4) & 7;               // 16B slot in row
            int sch = slot ^ (row & 7);             // swizzled source chunk
            // A: W2 row (m0+row), 128B slice at it*128, chunk sch
            GLOAD16(Ab + (size_t)row * 1536 + it * 128 + sch * 16, (char*)As + fb);
            // B: sch<4 -> Xhi kg=it*4+sch ; else Xlo kg=it*4+sch-4
            const uint4* plane = (sch < 4) ? XH : XL;
            GLOAD16(plane + ((size_t)(it * 4 + (sch & 3))) * PVOL + row, (char*)Bs + fb);
        }
        __syncthreads();

        bs8 ah[4], al[4], bh[4], bl[4];
        #pragma unroll
        for (int f = 0; f < 4; ++f) {
            int rowA = wr * 64 + f * 16 + l15;
            int swzA = (rowA & 7) << 4;
            ah[f] = *(const bs8*)((const char*)As + rowA * 128 + ((lq * 16) ^ swzA));
            al[f] = *(const bs8*)((const char*)As + rowA * 128 + ((64 + lq * 16) ^ swzA));
            int rowB = wc * 64 + f * 16 + l15;
            int swzB = (rowB & 7) << 4;
            bh[f] = *(const bs8*)((const char*)Bs + rowB * 128 + ((lq * 16) ^ swzB));
            bl[f] = *(const bs8*)((const char*)Bs + rowB * 128 + ((64 + lq * 16) ^ swzB));
        }
        #pragma unroll
        for (int fm = 0; fm < 4; ++fm)
            #pragma unroll
            for (int fn = 0; fn < 4; ++fn) {
                acc[fm][fn] = __builtin_amdgcn_mfma_f32_16x16x32_bf16(ah[fm], bh[fn], acc[fm][fn], 0, 0, 0);
                acc[fm][fn] = __builtin_amdgcn_mfma_f32_16x16x32_bf16(ah[fm], bl[fn], acc[fm][fn], 0, 0, 0);
                acc[fm][fn] = __builtin_amdgcn_mfma_f32_16x16x32_bf16(al[fm], bh[fn], acc[fm][fn], 0, 0, 0);
            }
        __syncthreads();
    }

    float* Yp = Y + (size_t)b * MCH * PVOL;
    #pragma unroll
    for (int fm = 0; fm < 4; ++fm)
        #pragma unroll
        for (int j = 0; j < 4; ++j) {
            int m = m0 + wr * 64 + fm * 16 + lq * 4 + j;
            float bias = gbias[m / GG];
            #pragma unroll
            for (int fn = 0; fn < 4; ++fn) {
                int n = n0 + wc * 64 + fn * 16 + l15;
                Yp[(size_t)m * PVOL + n] = acc[fm][fn][j] + bias;
            }
        }
}

// ---------------------------------------------------------------------------
// dwconv v2 (unchanged): depthwise 3x3x3 + t_bias + leaky_relu, z-vec float4.
// ---------------------------------------------------------------------------
__global__ __launch_bounds__(256) void dwconv(const float* __restrict__ Y,
                                              const float* __restrict__ Wt,
                                              const float* __restrict__ tb,
                                              float* __restrict__ O) {
    const int x0 = blockIdx.x * 4;
    const int c  = blockIdx.y;
    const int b  = blockIdx.z;
    const float* __restrict__ Yc = Y + ((size_t)(b * MCH + c)) * PVOL;
    float* __restrict__ Oc = O + ((size_t)(b * MCH + c)) * PVOL;

    __shared__ float s[6][34][40];
    __shared__ float taps[27];
    const int t = threadIdx.x;

    {
        float4 z4 = {0.f, 0.f, 0.f, 0.f};
        float4* sp = (float4*)s;
        for (int i = t; i < 2040; i += 256) sp[i] = z4;
    }
    if (t < 27) taps[t] = Wt[c * 27 + t];
    __syncthreads();

    const int y  = t >> 3;
    const int z0 = (t & 7) * 4;

    {
        float4 r[6];
        #pragma unroll
        for (int lx = 0; lx < 6; ++lx) {
            int x = x0 - 1 + lx;
            bool ok = (x >= 0 && x < 32);
            r[lx] = ok ? *(const float4*)&Yc[(size_t)x * 1024 + y * 32 + z0]
                       : (float4){0.f, 0.f, 0.f, 0.f};
        }
        #pragma unroll
        for (int lx = 0; lx < 6; ++lx)
            *(float4*)&s[lx][1 + y][4 + z0] = r[lx];
    }
    __syncthreads();

    const float t0 = tb[0];
    float w[27];
    #pragma unroll
    for (int j = 0; j < 27; ++j) w[j] = taps[j];

    float Wn[3][3][6];

    #define LOADWIN(slot, plane)                                              \
        {                                                                     \
            _Pragma("unroll")                                                 \
            for (int dy = 0; dy < 3; ++dy) {                                  \
                float4 a = *(const float4*)&s[plane][y + dy][z0];             \
                float4 bq = *(const float4*)&s[plane][y + dy][z0 + 4];        \
                float4 cq = *(const float4*)&s[plane][y + dy][z0 + 8];        \
                Wn[slot][dy][0] = a.w;                                        \
                Wn[slot][dy][1] = bq.x; Wn[slot][dy][2] = bq.y;               \
                Wn[slot][dy][3] = bq.z; Wn[slot][dy][4] = bq.w;               \
                Wn[slot][dy][5] = cq.x;                                       \
            }                                                                 \
        }

    LOADWIN(0, 0)
    LOADWIN(1, 1)

    #pragma unroll
    for (int xi = 0; xi < 4; ++xi) {
        LOADWIN((xi + 2) % 3, (xi + 2))
        const int s0 = xi % 3, s1 = (xi + 1) % 3, s2 = (xi + 2) % 3;
        float4 o;
        #pragma unroll
        for (int zz = 0; zz < 4; ++zz) {
            float a0 = 0.f, a1 = 0.f, a2 = 0.f;
            #pragma unroll
            for (int dy = 0; dy < 3; ++dy)
                #pragma unroll
                for (int dc = 0; dc < 3; ++dc) {
                    a0 += Wn[s0][dy][zz + dc] * w[dy * 3 + dc];
                    a1 += Wn[s1][dy][zz + dc] * w[9 + dy * 3 + dc];
                    a2 += Wn[s2][dy][zz + dc] * w[18 + dy * 3 + dc];
                }
            float v = a0 + a1 + a2 + t0;
            o[zz] = (v > 0.f) ? v : 0.01f * v;
        }
        *(float4*)&Oc[(size_t)(x0 + xi) * 1024 + y * 32 + z0] = o;
    }
    #undef LOADWIN
}

// ---------------------------------------------------------------------------
// Fallback fp32 path (unchanged)
// ---------------------------------------------------------------------------
__global__ void build_weights(const float* __restrict__ gw, const float* __restrict__ tw,
                              float* __restrict__ wmix, float* __restrict__ wt) {
    int idx = blockIdx.x * 256 + threadIdx.x;
    if (idx < MCH * KCH) {
        int c = idx / KCH, k = idx % KCH;
        int o = c / GG, z = c % GG;
        int i = k / GG, g = k % GG;
        wmix[idx] = gw[TAB.shift[z][g] * (OO * II) + o * II + i];
    } else {
        int r = idx - MCH * KCH;
        if (r < MCH * 27) {
            int c = r / 27, j = r % 27;
            wt[r] = tw[(c / GG) * 27 + TAB.rot[c % GG][j]];
        }
    }
}

#define BM 128
#define BN 128
#define BK 16

__global__ __launch_bounds__(256) void gemm_mix(const float* __restrict__ A,
                                                const float* __restrict__ X,
                                                const float* __restrict__ gbias,
                                                float* __restrict__ Y) {
    const int b  = blockIdx.z;
    const int m0 = blockIdx.y * BM;
    const int n0 = blockIdx.x * BN;
    const float* __restrict__ Bp = X + (size_t)b * KCH * PVOL;
    float* __restrict__ Yp = Y + (size_t)b * MCH * PVOL;

    __shared__ float Ash[BK][BM];
    __shared__ float Bsh[BK][BN];

    const int tid = threadIdx.x;
    const int tx = tid % 16;
    const int ty = tid / 16;

    float acc[8][8] = {};

    for (int k0 = 0; k0 < KCH; k0 += BK) {
        #pragma unroll
        for (int r = 0; r < 2; ++r) {
            int tt = tid + r * 256;
            int m = tt / 4;
            int kk = (tt % 4) * 4;
            float4 v = *(const float4*)&A[(m0 + m) * KCH + k0 + kk];
            Ash[kk + 0][m] = v.x; Ash[kk + 1][m] = v.y;
            Ash[kk + 2][m] = v.z; Ash[kk + 3][m] = v.w;
        }
        #pragma unroll
        for (int r = 0; r < 2; ++r) {
            int tt = tid + r * 256;
            int kk = tt / 32;
            int n = (tt % 32) * 4;
            *(float4*)&Bsh[kk][n] = *(const float4*)&Bp[(size_t)(k0 + kk) * PVOL + n0 + n];
        }
        __syncthreads();
        #pragma unroll
        for (int kk = 0; kk < BK; ++kk) {
            float af[8], bf[8];
            #pragma unroll
            for (int i = 0; i < 4; ++i) {
                af[i]     = Ash[kk][ty * 4 + i];
                af[4 + i] = Ash[kk][64 + ty * 4 + i];
                bf[i]     = Bsh[kk][tx * 4 + i];
                bf[4 + i] = Bsh[kk][64 + tx * 4 + i];
            }
            #pragma unroll
            for (int i = 0; i < 8; ++i)
                #pragma unroll
                for (int j = 0; j < 8; ++j)
                    acc[i][j] += af[i] * bf[j];
        }
        __syncthreads();
    }

    #pragma unroll
    for (int i = 0; i < 8; ++i) {
        int m = m0 + ((i < 4) ? (ty * 4 + i) : (64 + ty * 4 + (i - 4)));
        float bias = gbias[m / GG];
        float4 v0 = { acc[i][0] + bias, acc[i][1] + bias, acc[i][2] + bias, acc[i][3] + bias };
        float4 v1 = { acc[i][4] + bias, acc[i][5] + bias, acc[i][6] + bias, acc[i][7] + bias };
        *(float4*)&Yp[(size_t)m * PVOL + n0 + tx * 4]      = v0;
        *(float4*)&Yp[(size_t)m * PVOL + n0 + 64 + tx * 4] = v1;
    }
}

// ---------------------------------------------------------------------------
extern "C" void kernel_launch(void* const* d_in, const int* in_sizes, int n_in,
                              void* d_out, int out_size, void* d_ws, size_t ws_size,
                              hipStream_t stream) {
    const float* x  = (const float*)d_in[0];
    const float* gw = (const float*)d_in[1];
    const float* tw = (const float*)d_in[2];
    const float* gb = (const float*)d_in[3];
    const float* tb = (const float*)d_in[4];
    float* out = (float*)d_out;
    float* ws  = (float*)d_ws;

    // float offsets:
    //   wt   : 0          (10368)
    //   w2   : 10368      (294912 ushorts = 147456 floats)  [mfma] / wmix [fallback]
    //   y    : 157824     (25165824)
    //   xhi  : 25323648   (12582912 float-equiv)
    //   xlo  : 37906560   (12582912)           total 50489472 floats ~= 202 MB
    float*   wt   = ws;
    ushortx* w2   = (ushortx*)(ws + 10368);
    float*   wmix = ws + 10368;
    float*   y    = ws + 157824;
    uint4*   xhi  = (uint4*)(ws + 25323648);
    uint4*   xlo  = (uint4*)(ws + 37906560);

    const size_t need = (size_t)50489472 * 4;  // ~202 MB

    if (ws_size >= need) {
        build_weights2<<<dim3(617), dim3(256), 0, stream>>>(gw, tw, w2, wt);
        convert_x<<<dim3(128, KG, 2), dim3(256), 0, stream>>>(x, xhi, xlo);
        gemm_mfma<<<dim3(256, 3, 2), dim3(256), 0, stream>>>(w2, xhi, xlo, gb, y);
    } else {
        build_weights<<<dim3(617), dim3(256), 0, stream>>>(gw, tw, wmix, wt);
        gemm_mix<<<dim3(PVOL / BN, MCH / BM, 2), dim3(256), 0, stream>>>(wmix, x, gb, y);
    }
    dwconv<<<dim3(8, MCH, 2), dim3(256), 0, stream>>>(y, wt, tb, out);
}